// Round 1
// baseline (3307.971 us; speedup 1.0000x reference)
//
#include <hip/hip_runtime.h>
#include <math.h>

// ---------------------------------------------------------------------------
// NeuS-style fused renderer, f32 baseline.
// K0: weight transposes -> ws
// K2: per-32-sample tile: pos_enc, MLP fwd+bwd(grad wrt points), color MLP,
//     alpha. Writes sdf (d_out), a/rgb/normal (ws).
// K3: per-ray compositing (weights + segment sums).
// K4: random_sdfs.
// ---------------------------------------------------------------------------

#define TILE 32
#define NTHREADS 256
#define LDACT 260   // 260 % 32 == 4 -> breaks bank aliasing for row-indexed reads

struct alignas(16) SMemK2 {
    float act0[TILE * LDACT];   // h0 -> g1
    float act1[TILE * LDACT];   // h1 -> g2 -> g0 -> hc
    float enc [TILE * 40];      // [x(3), sin/cos(36)]
    float cin [TILE * 28];      // color input (25)
    float dirs[TILE * 4];
    float feats[TILE * 16];
    float nrm [TILE * 4];
    float wg2c0[256];           // Wg2[:,0]
};

// C[32 x 256] += A[32 x K] * B[K x 256]; A in LDS (row-major, ld=lda),
// B global row-major (ld=ldb). Thread microtile: 8 samples x 4 cols.
template<bool BIAS, bool RELU, bool MASK>
__device__ __forceinline__ void gemm_main(
    const float* sA, int lda,
    const float* __restrict__ B, int ldb, int K,
    const float* __restrict__ bias,
    float* sC, int ldc, int tid)
{
    const int sg = tid >> 6;        // wave id: samples sg*8 .. sg*8+7
    const int jg = tid & 63;        // cols jg*4 .. jg*4+3 (coalesced B)
    const int j0 = jg * 4;

    float acc[8][4];
#pragma unroll
    for (int i = 0; i < 8; ++i)
#pragma unroll
        for (int j = 0; j < 4; ++j) acc[i][j] = 0.f;

    int k = 0;
    float4 bv[4];
    if (k + 4 <= K) {
#pragma unroll
        for (int kk = 0; kk < 4; ++kk)
            bv[kk] = *(const float4*)(B + (size_t)(k + kk) * ldb + j0);
    }
    for (; k + 4 <= K; k += 4) {
        float4 bn[4];
        const bool havenext = (k + 8 <= K);
        if (havenext) {
#pragma unroll
            for (int kk = 0; kk < 4; ++kk)
                bn[kk] = *(const float4*)(B + (size_t)(k + 4 + kk) * ldb + j0);
        }
        float bm[4][4];
#pragma unroll
        for (int kk = 0; kk < 4; ++kk) {
            bm[kk][0] = bv[kk].x; bm[kk][1] = bv[kk].y;
            bm[kk][2] = bv[kk].z; bm[kk][3] = bv[kk].w;
        }
#pragma unroll
        for (int i = 0; i < 8; ++i) {
            const int s = sg * 8 + i;
            float4 av = *(const float4*)(sA + s * lda + k);  // LDS broadcast b128
            float am[4] = {av.x, av.y, av.z, av.w};
#pragma unroll
            for (int kk = 0; kk < 4; ++kk)
#pragma unroll
                for (int j = 0; j < 4; ++j)
                    acc[i][j] += am[kk] * bm[kk][j];
        }
        if (havenext) {
#pragma unroll
            for (int kk = 0; kk < 4; ++kk) bv[kk] = bn[kk];
        }
    }
    for (; k < K; ++k) {  // tail (K=39, K=25)
        float b0 = B[(size_t)k * ldb + j0 + 0];
        float b1 = B[(size_t)k * ldb + j0 + 1];
        float b2 = B[(size_t)k * ldb + j0 + 2];
        float b3 = B[(size_t)k * ldb + j0 + 3];
#pragma unroll
        for (int i = 0; i < 8; ++i) {
            float a = sA[(sg * 8 + i) * lda + k];
            acc[i][0] += a * b0; acc[i][1] += a * b1;
            acc[i][2] += a * b2; acc[i][3] += a * b3;
        }
    }

    float4 bsv = make_float4(0.f, 0.f, 0.f, 0.f);
    if (BIAS) bsv = *(const float4*)(bias + j0);
#pragma unroll
    for (int i = 0; i < 8; ++i) {
        const int s = sg * 8 + i;
        float r0 = acc[i][0] + bsv.x;
        float r1 = acc[i][1] + bsv.y;
        float r2 = acc[i][2] + bsv.z;
        float r3 = acc[i][3] + bsv.w;
        if (RELU) {
            r0 = fmaxf(r0, 0.f); r1 = fmaxf(r1, 0.f);
            r2 = fmaxf(r2, 0.f); r3 = fmaxf(r3, 0.f);
        }
        if (MASK) {  // gate by (old C > 0): relu' of the stored activation
            float4 old = *(const float4*)(sC + s * ldc + j0);
            r0 = (old.x > 0.f) ? r0 : 0.f;
            r1 = (old.y > 0.f) ? r1 : 0.f;
            r2 = (old.z > 0.f) ? r2 : 0.f;
            r3 = (old.w > 0.f) ? r3 : 0.f;
        }
        *(float4*)(sC + s * ldc + j0) = make_float4(r0, r1, r2, r3);
    }
}

__global__ void k0_transpose(const float* __restrict__ Wg0,
                             const float* __restrict__ Wg1,
                             float* __restrict__ Wg1T,
                             float* __restrict__ Wg0T64)
{
    int gid = blockIdx.x * blockDim.x + threadIdx.x;
    if (gid < 65536) {
        int j = gid >> 8, k = gid & 255;
        Wg1T[j * 256 + k] = Wg1[k * 256 + j];       // Wg1T[j][k] = Wg1[k][j]
    } else if (gid < 65536 + 16384) {
        int i = gid - 65536;
        int k = i >> 6, m = i & 63;                  // Wg0T64[k][m] = Wg0[m][k]
        Wg0T64[k * 64 + m] = (m < 39) ? Wg0[m * 256 + k] : 0.f;
    }
}

__global__ __launch_bounds__(256, 2) void k2_mlp(
    const float* __restrict__ rays_o, const float* __restrict__ rays_d,
    const int*   __restrict__ ray_idx, const float* __restrict__ t_starts,
    const float* __restrict__ s_var,
    const float* __restrict__ Wg0, const float* __restrict__ bg0,
    const float* __restrict__ Wg1, const float* __restrict__ bg1,
    const float* __restrict__ Wg2, const float* __restrict__ bg2,
    const float* __restrict__ Wc0, const float* __restrict__ bc0,
    const float* __restrict__ Wc1, const float* __restrict__ bc1,
    const float* __restrict__ Wg1T, const float* __restrict__ Wg0T64,
    float* __restrict__ out_sdf, float* __restrict__ ws_a,
    float* __restrict__ ws_rgb, float* __restrict__ ws_nrm,
    int Nsamp)
{
    __shared__ SMemK2 sm;
    const int tid = threadIdx.x;
    const int n0 = blockIdx.x * TILE;

    // ---- P0: points, dirs; stage Wg2[:,0]
    sm.wg2c0[tid] = Wg2[tid * 16];
    if (tid < TILE) {
        int n = n0 + tid; if (n >= Nsamp) n = Nsamp - 1;
        int ri = ray_idx[n];
        float dx = rays_d[ri * 3 + 0], dy = rays_d[ri * 3 + 1], dz = rays_d[ri * 3 + 2];
        float inv = 1.f / (sqrtf(dx * dx + dy * dy + dz * dz) + 1e-10f);
        dx *= inv; dy *= inv; dz *= inv;
        float mid = t_starts[n] + 0.0025f;
        float px = rays_o[ri * 3 + 0] + dx * mid;
        float py = rays_o[ri * 3 + 1] + dy * mid;
        float pz = rays_o[ri * 3 + 2] + dz * mid;
        sm.dirs[tid * 4 + 0] = dx; sm.dirs[tid * 4 + 1] = dy; sm.dirs[tid * 4 + 2] = dz;
        sm.enc[tid * 40 + 0] = px; sm.enc[tid * 40 + 1] = py; sm.enc[tid * 40 + 2] = pz;
    }
    __syncthreads();

    // ---- P1: positional encoding  (col 3 + f*6 + r : r<3 sin, r>=3 cos)
    for (int w = tid; w < TILE * 36; w += NTHREADS) {
        int s = w & (TILE - 1);
        int e = w >> 5;                    // 0..35
        int f = e / 6, r = e - f * 6;
        float freq = 3.14159265358979323846f * (float)(1 << f);
        int d = (r < 3) ? r : r - 3;
        float x = sm.enc[s * 40 + d];
        float arg = freq * x;
        sm.enc[s * 40 + 3 + e] = (r < 3) ? sinf(arg) : cosf(arg);
    }
    __syncthreads();

    // ---- P2: h0 = relu(enc @ Wg0 + bg0)
    gemm_main<true, true, false>(sm.enc, 40, Wg0, 256, 39, bg0, sm.act0, LDACT, tid);
    __syncthreads();
    // ---- P3: h1 = relu(h0 @ Wg1 + bg1)
    gemm_main<true, true, false>(sm.act0, LDACT, Wg1, 256, 256, bg1, sm.act1, LDACT, tid);
    __syncthreads();

    // ---- P4: feats = h1 @ Wg2 + bg2 ; sdf = feats[:,0]
    {
        int s = tid >> 3, jq = tid & 7, j0 = jq * 2;
        float acc0 = 0.f, acc1 = 0.f;
        for (int kk = 0; kk < 256; kk += 4) {
            float4 av = *(const float4*)(sm.act1 + s * LDACT + kk);
            float2 b0 = *(const float2*)(Wg2 + (kk + 0) * 16 + j0);
            float2 b1 = *(const float2*)(Wg2 + (kk + 1) * 16 + j0);
            float2 b2 = *(const float2*)(Wg2 + (kk + 2) * 16 + j0);
            float2 b3 = *(const float2*)(Wg2 + (kk + 3) * 16 + j0);
            acc0 += av.x * b0.x + av.y * b1.x + av.z * b2.x + av.w * b3.x;
            acc1 += av.x * b0.y + av.y * b1.y + av.z * b2.y + av.w * b3.y;
        }
        float v0 = acc0 + bg2[j0], v1 = acc1 + bg2[j0 + 1];
        sm.feats[s * 16 + j0] = v0;
        sm.feats[s * 16 + j0 + 1] = v1;
        int n = n0 + s;
        if (jq == 0 && n < Nsamp) out_sdf[n] = v0;
    }
    __syncthreads();

    // ---- P5: g2 = (h1>0) ? Wg2[:,0] : 0   (in place over act1)
    for (int idx = tid; idx < TILE * 256; idx += NTHREADS) {
        int s = idx >> 8, j = idx & 255;
        float h = sm.act1[s * LDACT + j];
        sm.act1[s * LDACT + j] = (h > 0.f) ? sm.wg2c0[j] : 0.f;
    }
    __syncthreads();

    // ---- P6: g1 = (g2 @ Wg1^T) * (h0>0)   (mask from old act0, overwrite)
    gemm_main<false, false, true>(sm.act1, LDACT, Wg1T, 256, 256, nullptr, sm.act0, LDACT, tid);
    __syncthreads();

    // ---- P7: g0 = g1 @ Wg0^T  -> act1 cols 0..63 (39 valid)
    {
        int jg = tid & 15, sg = tid >> 4;
        int j0 = jg * 4, s0 = sg * 2;
        float acc[2][4];
#pragma unroll
        for (int i = 0; i < 2; ++i)
#pragma unroll
            for (int j = 0; j < 4; ++j) acc[i][j] = 0.f;
        for (int k = 0; k < 256; k += 4) {
            float4 bv[4];
#pragma unroll
            for (int kk = 0; kk < 4; ++kk)
                bv[kk] = *(const float4*)(Wg0T64 + (size_t)(k + kk) * 64 + j0);
            float bm[4][4];
#pragma unroll
            for (int kk = 0; kk < 4; ++kk) {
                bm[kk][0] = bv[kk].x; bm[kk][1] = bv[kk].y;
                bm[kk][2] = bv[kk].z; bm[kk][3] = bv[kk].w;
            }
#pragma unroll
            for (int i = 0; i < 2; ++i) {
                float4 av = *(const float4*)(sm.act0 + (s0 + i) * LDACT + k);
                float am[4] = {av.x, av.y, av.z, av.w};
#pragma unroll
                for (int kk = 0; kk < 4; ++kk)
#pragma unroll
                    for (int j = 0; j < 4; ++j)
                        acc[i][j] += am[kk] * bm[kk][j];
            }
        }
#pragma unroll
        for (int i = 0; i < 2; ++i)
            *(float4*)(sm.act1 + (s0 + i) * LDACT + j0) =
                make_float4(acc[i][0], acc[i][1], acc[i][2], acc[i][3]);
    }
    __syncthreads();

    // ---- P7b: grad through encoding, normal, alpha
    if (tid < TILE) {
        int s = tid;
        float g[3];
#pragma unroll
        for (int d = 0; d < 3; ++d) g[d] = sm.act1[s * LDACT + d];
#pragma unroll
        for (int f = 0; f < 6; ++f) {
            float freq = 3.14159265358979323846f * (float)(1 << f);
#pragma unroll
            for (int d = 0; d < 3; ++d) {
                float gs = sm.act1[s * LDACT + 3 + f * 6 + d];
                float gc = sm.act1[s * LDACT + 3 + f * 6 + 3 + d];
                float sv = sm.enc[s * 40 + 3 + f * 6 + d];
                float cv = sm.enc[s * 40 + 3 + f * 6 + 3 + d];
                g[d] += freq * (gs * cv - gc * sv);
            }
        }
        float gl = sqrtf(g[0] * g[0] + g[1] * g[1] + g[2] * g[2]);
        float invl = 1.f / (gl + 1e-10f);
        float nx = g[0] * invl, ny = g[1] * invl, nz = g[2] * invl;
        sm.nrm[s * 4 + 0] = nx; sm.nrm[s * 4 + 1] = ny; sm.nrm[s * 4 + 2] = nz;
        float dx = sm.dirs[s * 4 + 0], dy = sm.dirs[s * 4 + 1], dz = sm.dirs[s * 4 + 2];
        float dsdt = fminf(g[0] * dx + g[1] * dy + g[2] * dz, 0.f);
        float sdf = sm.feats[s * 16 + 0];
        float inv_s = __expf(s_var[0]);
        inv_s = fminf(fmaxf(inv_s, 1e-6f), 1e6f);
        float cdf = 1.f / (1.f + __expf(-inv_s * sdf));
        float rho = fmaxf(inv_s * (cdf - 1.f) * dsdt, 0.f);
        float alpha = 1.f - __expf(-rho * 0.005f);
        float a = fminf(fmaxf(alpha, 0.f), 1.f - 1e-7f);
        int n = n0 + s;
        if (n < Nsamp) {
            ws_a[n] = a;
            ws_nrm[n * 3 + 0] = nx; ws_nrm[n * 3 + 1] = ny; ws_nrm[n * 3 + 2] = nz;
        }
    }
    __syncthreads();

    // ---- P8a: cin = [t_dirs(3), feats(16), points(3), normal(3)]
    for (int idx = tid; idx < TILE * 25; idx += NTHREADS) {
        int s = idx & 31, c = idx >> 5;
        float v;
        if      (c < 3)  v = sm.dirs[s * 4 + c];
        else if (c < 19) v = sm.feats[s * 16 + (c - 3)];
        else if (c < 22) v = sm.enc[s * 40 + (c - 19)];
        else             v = sm.nrm[s * 4 + (c - 22)];
        sm.cin[s * 28 + c] = v;
    }
    __syncthreads();

    // ---- P8: hc = relu(cin @ Wc0 + bc0)  -> act1
    gemm_main<true, true, false>(sm.cin, 28, Wc0, 256, 25, bc0, sm.act1, LDACT, tid);
    __syncthreads();

    // ---- P9: rgb = sigmoid(hc @ Wc1 + bc1)
    {
        int s = tid >> 3, dq = tid & 7;
        if (dq < 3) {
            float acc = 0.f;
            for (int k = 0; k < 256; k += 4) {
                float4 av = *(const float4*)(sm.act1 + s * LDACT + k);
                float w0 = Wc1[(k + 0) * 3 + dq];
                float w1 = Wc1[(k + 1) * 3 + dq];
                float w2 = Wc1[(k + 2) * 3 + dq];
                float w3 = Wc1[(k + 3) * 3 + dq];
                acc += av.x * w0 + av.y * w1 + av.z * w2 + av.w * w3;
            }
            float rgb = 1.f / (1.f + __expf(-(acc + bc1[dq])));
            int n = n0 + s;
            if (n < Nsamp) ws_rgb[n * 3 + dq] = rgb;
        }
    }
}

__global__ void k3_composite(
    const int* __restrict__ ray_idx, const float* __restrict__ t_starts,
    const float* __restrict__ ws_a, const float* __restrict__ ws_rgb,
    const float* __restrict__ ws_nrm,
    float* __restrict__ out_pc, float* __restrict__ out_pn,
    float* __restrict__ out_op, float* __restrict__ out_dp,
    float* __restrict__ out_w, int n_rays, int Nsamp)
{
    int r = blockIdx.x * blockDim.x + threadIdx.x;
    if (r >= n_rays) return;
    int lo = 0, hi = Nsamp;
    while (lo < hi) { int m = (lo + hi) >> 1; if (ray_idx[m] < r) lo = m + 1; else hi = m; }
    int start = lo;
    hi = Nsamp;
    while (lo < hi) { int m = (lo + hi) >> 1; if (ray_idx[m] < r + 1) lo = m + 1; else hi = m; }
    int end = lo;

    float T = 1.f, aco = 0.f, acd = 0.f;
    float c0 = 0.f, c1 = 0.f, c2 = 0.f, nx = 0.f, ny = 0.f, nz = 0.f;
    for (int n = start; n < end; ++n) {
        float a = ws_a[n];
        float w = a * T;
        T *= (1.f - a);
        out_w[n] = w;
        float mid = t_starts[n] + 0.0025f;
        aco += w; acd += w * mid;
        c0 += w * ws_rgb[n * 3 + 0];
        c1 += w * ws_rgb[n * 3 + 1];
        c2 += w * ws_rgb[n * 3 + 2];
        nx += w * ws_nrm[n * 3 + 0];
        ny += w * ws_nrm[n * 3 + 1];
        nz += w * ws_nrm[n * 3 + 2];
    }
    out_op[r] = aco;
    out_dp[r] = acd;
    out_pc[r * 3 + 0] = c0; out_pc[r * 3 + 1] = c1; out_pc[r * 3 + 2] = c2;
    float nl = sqrtf(nx * nx + ny * ny + nz * nz);
    float inv = 1.f / (nl + 1e-10f);
    out_pn[r * 3 + 0] = nx * inv; out_pn[r * 3 + 1] = ny * inv; out_pn[r * 3 + 2] = nz * inv;
}

__global__ __launch_bounds__(256) void k4_random(
    const float* __restrict__ pts,
    const float* __restrict__ Wg0, const float* __restrict__ bg0,
    const float* __restrict__ Wg1, const float* __restrict__ bg1,
    const float* __restrict__ Wg2, const float* __restrict__ bg2,
    float* __restrict__ out_rs, int n_rand)
{
    __shared__ float enc[40];
    __shared__ float h[256];
    __shared__ float red[256];
    int b = blockIdx.x;
    if (b >= n_rand) return;
    int tid = threadIdx.x;
    if (tid < 39) {
        int c = tid;
        float v;
        if (c < 3) v = pts[b * 3 + c];
        else {
            int e = c - 3, f = e / 6, r = e - f * 6;
            float freq = 3.14159265358979323846f * (float)(1 << f);
            int d = (r < 3) ? r : r - 3;
            float x = pts[b * 3 + d];
            v = (r < 3) ? sinf(freq * x) : cosf(freq * x);
        }
        enc[c] = v;
    }
    __syncthreads();
    {
        float z = bg0[tid];
        for (int m = 0; m < 39; ++m) z += enc[m] * Wg0[m * 256 + tid];
        h[tid] = fmaxf(z, 0.f);
    }
    __syncthreads();
    {
        float z = bg1[tid];
        for (int k = 0; k < 256; ++k) z += h[k] * Wg1[k * 256 + tid];
        float h1 = fmaxf(z, 0.f);
        red[tid] = h1 * Wg2[tid * 16];   // Wg2[:,0]
    }
    __syncthreads();
    for (int off = 128; off > 0; off >>= 1) {
        if (tid < off) red[tid] += red[tid + off];
        __syncthreads();
    }
    if (tid == 0) out_rs[b] = red[0] + bg2[0];
}

extern "C" void kernel_launch(void* const* d_in, const int* in_sizes, int n_in,
                              void* d_out, int out_size, void* d_ws, size_t ws_size,
                              hipStream_t stream)
{
    const float* rays_o   = (const float*)d_in[0];
    const float* rays_d   = (const float*)d_in[1];
    const int*   ray_idx  = (const int*)  d_in[2];
    const float* t_starts = (const float*)d_in[3];
    const float* rpts     = (const float*)d_in[4];
    const float* s_var    = (const float*)d_in[5];
    const float* Wg0 = (const float*)d_in[6];  const float* bg0 = (const float*)d_in[7];
    const float* Wg1 = (const float*)d_in[8];  const float* bg1 = (const float*)d_in[9];
    const float* Wg2 = (const float*)d_in[10]; const float* bg2 = (const float*)d_in[11];
    const float* Wc0 = (const float*)d_in[12]; const float* bc0 = (const float*)d_in[13];
    const float* Wc1 = (const float*)d_in[14]; const float* bc1 = (const float*)d_in[15];

    const int n_rays = in_sizes[0] / 3;
    const int Ns     = in_sizes[2];
    const int n_rand = in_sizes[4] / 3;

    float* out  = (float*)d_out;
    float* o_pc = out;
    float* o_pn = out + (size_t)3 * n_rays;
    float* o_op = out + (size_t)6 * n_rays;
    float* o_dp = out + (size_t)7 * n_rays;
    float* o_w  = out + (size_t)8 * n_rays;
    float* o_sdf = o_w + Ns;
    float* o_rs  = o_sdf + Ns;

    float* wsf    = (float*)d_ws;
    float* Wg1T   = wsf;                       // 65536
    float* Wg0T64 = wsf + 65536;               // 16384
    float* ws_a   = wsf + 65536 + 16384;       // Ns
    float* ws_rgb = ws_a + Ns;                 // 3*Ns
    float* ws_nrm = ws_rgb + (size_t)3 * Ns;   // 3*Ns   (total ~15 MB)

    hipLaunchKernelGGL(k0_transpose, dim3(320), dim3(256), 0, stream,
                       Wg0, Wg1, Wg1T, Wg0T64);
    hipLaunchKernelGGL(k2_mlp, dim3((Ns + TILE - 1) / TILE), dim3(NTHREADS), 0, stream,
                       rays_o, rays_d, ray_idx, t_starts, s_var,
                       Wg0, bg0, Wg1, bg1, Wg2, bg2, Wc0, bc0, Wc1, bc1,
                       Wg1T, Wg0T64, o_sdf, ws_a, ws_rgb, ws_nrm, Ns);
    hipLaunchKernelGGL(k4_random, dim3(n_rand), dim3(256), 0, stream,
                       rpts, Wg0, bg0, Wg1, bg1, Wg2, bg2, o_rs, n_rand);
    hipLaunchKernelGGL(k3_composite, dim3((n_rays + 255) / 256), dim3(256), 0, stream,
                       ray_idx, t_starts, ws_a, ws_rgb, ws_nrm,
                       o_pc, o_pn, o_op, o_dp, o_w, n_rays, Ns);
}

// Round 2
// 1066.893 us; speedup vs baseline: 3.1006x; 3.1006x over previous
//
#include <hip/hip_runtime.h>
#include <math.h>

// ---------------------------------------------------------------------------
// NeuS-style fused renderer, split-f16 MFMA version.
// All GEMMs run as v_mfma_f32_16x16x32_f16 with hi/lo split operands
// (3 MFMAs per logical tile -> ~f32 accuracy at 1/3 of 2.5PF).
// K0: pack weights into B-fragment layout (hi|lo) in ws.
// K2: per-32-sample tile: pos_enc, geometry MLP fwd+bwd, color MLP, alpha.
// K3: per-ray compositing. K4: random_sdfs.
// ---------------------------------------------------------------------------

#define TILE 32
#define NTHREADS 256
#define LDACT 260   // (m*260+q*8)%32 -> only 2-way bank alias (free)
#define LDENC 68

typedef _Float16 half8 __attribute__((ext_vector_type(8)));
typedef float f32x4 __attribute__((ext_vector_type(4)));

struct alignas(16) SMemK2 {
    float act0[TILE * LDACT];   // h0 -> g1 -> cin(overlay, ld36)
    float act1[TILE * LDACT];   // h1 -> (g0 cols 0..63) -> hc
    float enc [TILE * LDENC];   // [x(3), sin/cos(36), 0-pad to 63]
    float dirs[TILE * 4];
    float feats[TILE * 16];
    float nrm [TILE * 4];
    float wg2c0[256];           // Wg2[:,0]
};

__device__ __forceinline__ void load8(const float* p, float v[8]) {
    float4 a = *(const float4*)p, b = *(const float4*)(p + 4);
    v[0]=a.x; v[1]=a.y; v[2]=a.z; v[3]=a.w; v[4]=b.x; v[5]=b.y; v[6]=b.z; v[7]=b.w;
}

__device__ __forceinline__ void split8(const float v[8], half8& hi, half8& lo) {
#pragma unroll
    for (int j = 0; j < 8; ++j) {
        float x = v[j];
        _Float16 h = (_Float16)x;
        hi[j] = h;
        lo[j] = (_Float16)(x - (float)h);
    }
}

// Wave-level GEMM: C[32 x Ncols] (sub-block mt*16..+16, cols ntbase*16..+NTPW*16)
// A: f32 in LDS (row s, ld lda). B: packed frag layout in global
//   Bp[((nt*kiters + kit)*64 + lane)*16 + (0..7 hi | 8..15 lo)].
template<int NTPW, bool BIAS, bool RELU, bool MASK, bool AMASKG2>
__device__ __forceinline__ void mfma_gemm(
    const float* sA, int lda, const float* wg2c0,
    const _Float16* __restrict__ Bp, int kiters,
    const float* __restrict__ bias,
    float* sC, int ldc,
    int lane, int mt, int ntbase)
{
    f32x4 acc[NTPW];
#pragma unroll
    for (int t = 0; t < NTPW; ++t) acc[t] = (f32x4){0.f, 0.f, 0.f, 0.f};
    const int m  = mt * 16 + (lane & 15);
    const int q8 = (lane >> 4) * 8;
    const _Float16* bbase = Bp + (size_t)ntbase * kiters * 1024 + lane * 16;

    for (int kit = 0; kit < kiters; ++kit) {
        float v[8];
        load8(sA + m * lda + kit * 32 + q8, v);
        if (AMASKG2) {
            float wv[8];
            load8(wg2c0 + kit * 32 + q8, wv);   // broadcast within quad
#pragma unroll
            for (int j = 0; j < 8; ++j) v[j] = (v[j] > 0.f) ? wv[j] : 0.f;
        }
        half8 ah, al;
        split8(v, ah, al);
        const _Float16* bp = bbase + (size_t)kit * 1024;
#pragma unroll
        for (int t = 0; t < NTPW; ++t) {
            const _Float16* bt = bp + (size_t)t * kiters * 1024;
            half8 bh = *(const half8*)(bt);
            half8 bl = *(const half8*)(bt + 8);
            acc[t] = __builtin_amdgcn_mfma_f32_16x16x32_f16(al, bh, acc[t], 0, 0, 0);
            acc[t] = __builtin_amdgcn_mfma_f32_16x16x32_f16(ah, bl, acc[t], 0, 0, 0);
            acc[t] = __builtin_amdgcn_mfma_f32_16x16x32_f16(ah, bh, acc[t], 0, 0, 0);
        }
    }
    const int col = lane & 15, q = lane >> 4;
#pragma unroll
    for (int t = 0; t < NTPW; ++t) {
        int j = (ntbase + t) * 16 + col;
        float bs = BIAS ? bias[j] : 0.f;
#pragma unroll
        for (int r = 0; r < 4; ++r) {
            int s = mt * 16 + q * 4 + r;
            float vv = acc[t][r] + bs;
            if (RELU) vv = fmaxf(vv, 0.f);
            if (MASK) { float old = sC[s * ldc + j]; vv = (old > 0.f) ? vv : 0.f; }
            sC[s * ldc + j] = vv;
        }
    }
}

// ---------------- K0: pack weights to (hi|lo) B-fragment layout -------------
__global__ __launch_bounds__(256) void k0_pack(
    const float* __restrict__ Wg0, const float* __restrict__ Wg1,
    const float* __restrict__ Wg2, const float* __restrict__ Wc0,
    const float* __restrict__ Wc1,
    _Float16* __restrict__ Wg0p, _Float16* __restrict__ Wg1p,
    _Float16* __restrict__ Wg1Tp, _Float16* __restrict__ Wg0Tp,
    _Float16* __restrict__ Wc0p, _Float16* __restrict__ Wg2p,
    _Float16* __restrict__ Wc1p)
{
    int gid = blockIdx.x * 256 + threadIdx.x;
    if (gid >= 180224) return;
    int idx, kiters, mode;
    _Float16* dst;
    if      (gid <  16384) { idx = gid;          kiters = 2; dst = Wg0p;  mode = 0; }
    else if (gid <  81920) { idx = gid -  16384; kiters = 8; dst = Wg1p;  mode = 1; }
    else if (gid < 147456) { idx = gid -  81920; kiters = 8; dst = Wg1Tp; mode = 2; }
    else if (gid < 163840) { idx = gid - 147456; kiters = 8; dst = Wg0Tp; mode = 3; }
    else if (gid < 172032) { idx = gid - 163840; kiters = 1; dst = Wc0p;  mode = 4; }
    else if (gid < 176128) { idx = gid - 172032; kiters = 8; dst = Wg2p;  mode = 5; }
    else                   { idx = gid - 176128; kiters = 8; dst = Wc1p;  mode = 6; }
    int j = idx & 7, lane = (idx >> 3) & 63, rest = idx >> 9;
    int kit = rest % kiters, nt = rest / kiters;
    int k = kit * 32 + ((lane >> 4) << 3) + j;
    int n = (nt << 4) + (lane & 15);
    float val = 0.f;
    switch (mode) {
        case 0: val = (k < 39) ? Wg0[k * 256 + n] : 0.f; break;
        case 1: val = Wg1[k * 256 + n]; break;
        case 2: val = Wg1[n * 256 + k]; break;                // Wg1^T
        case 3: val = (n < 39) ? Wg0[n * 256 + k] : 0.f; break; // Wg0^T (N pad 64)
        case 4: val = (k < 25) ? Wc0[k * 256 + n] : 0.f; break;
        case 5: val = Wg2[k * 16 + n]; break;
        case 6: val = (n < 3) ? Wc1[k * 3 + n] : 0.f; break;
    }
    _Float16 h = (_Float16)val;
    _Float16 l = (_Float16)(val - (float)h);
    int off = ((nt * kiters + kit) * 64 + lane) * 16 + j;
    dst[off] = h;
    dst[off + 8] = l;
}

// ---------------- K2: the fused MLP ----------------------------------------
__global__ __launch_bounds__(256, 2) void k2_mlp(
    const float* __restrict__ rays_o, const float* __restrict__ rays_d,
    const int*   __restrict__ ray_idx, const float* __restrict__ t_starts,
    const float* __restrict__ s_var,
    const float* __restrict__ bg0, const float* __restrict__ bg1,
    const float* __restrict__ Wg2, const float* __restrict__ bg2,
    const float* __restrict__ bc0, const float* __restrict__ bc1,
    const _Float16* __restrict__ Wg0p, const _Float16* __restrict__ Wg1p,
    const _Float16* __restrict__ Wg1Tp, const _Float16* __restrict__ Wg0Tp,
    const _Float16* __restrict__ Wc0p, const _Float16* __restrict__ Wg2p,
    const _Float16* __restrict__ Wc1p,
    float* __restrict__ out_sdf, float* __restrict__ ws_a,
    float* __restrict__ ws_rgb, float* __restrict__ ws_nrm,
    int Nsamp)
{
    __shared__ SMemK2 sm;
    const int tid = threadIdx.x;
    const int lane = tid & 63;
    const int w = tid >> 6;
    const int n0 = blockIdx.x * TILE;

    // ---- P0: points, dirs, Wg2[:,0]
    sm.wg2c0[tid] = Wg2[tid * 16];
    if (tid < TILE) {
        int n = n0 + tid; if (n >= Nsamp) n = Nsamp - 1;
        int ri = ray_idx[n];
        float dx = rays_d[ri * 3 + 0], dy = rays_d[ri * 3 + 1], dz = rays_d[ri * 3 + 2];
        float inv = 1.f / (sqrtf(dx * dx + dy * dy + dz * dz) + 1e-10f);
        dx *= inv; dy *= inv; dz *= inv;
        float mid = t_starts[n] + 0.0025f;
        sm.dirs[tid * 4 + 0] = dx; sm.dirs[tid * 4 + 1] = dy; sm.dirs[tid * 4 + 2] = dz;
        sm.enc[tid * LDENC + 0] = rays_o[ri * 3 + 0] + dx * mid;
        sm.enc[tid * LDENC + 1] = rays_o[ri * 3 + 1] + dy * mid;
        sm.enc[tid * LDENC + 2] = rays_o[ri * 3 + 2] + dz * mid;
    }
    __syncthreads();

    // ---- P1: positional encoding + zero pad cols 39..67
    for (int i = tid; i < TILE * 36; i += NTHREADS) {
        int s = i & (TILE - 1);
        int e = i >> 5;                    // 0..35
        int f = e / 6, r = e - f * 6;
        float freq = 3.14159265358979323846f * (float)(1 << f);
        int d = (r < 3) ? r : r - 3;
        float x = sm.enc[s * LDENC + d];
        sm.enc[s * LDENC + 3 + e] = (r < 3) ? sinf(freq * x) : cosf(freq * x);
    }
    for (int i = tid; i < TILE * 29; i += NTHREADS) {
        int s = i / 29, c = 39 + (i - s * 29);
        sm.enc[s * LDENC + c] = 0.f;
    }
    __syncthreads();

    // ---- P2: h0 = relu(enc @ Wg0 + bg0) -> act0   (K=64 padded)
    mfma_gemm<8, true, true, false, false>(sm.enc, LDENC, nullptr, Wg0p, 2, bg0,
                                           sm.act0, LDACT, lane, w & 1, (w >> 1) * 8);
    __syncthreads();

    // ---- P3: h1 = relu(h0 @ Wg1 + bg1) -> act1
    mfma_gemm<8, true, true, false, false>(sm.act0, LDACT, nullptr, Wg1p, 8, bg1,
                                           sm.act1, LDACT, lane, w & 1, (w >> 1) * 8);
    __syncthreads();

    // ---- P4: feats = h1 @ Wg2 + bg2 (waves 0,1); sdf out
    if (w < 2) {
        f32x4 acc = (f32x4){0.f, 0.f, 0.f, 0.f};
        const int m = w * 16 + (lane & 15);
        const int q8 = (lane >> 4) * 8;
        const _Float16* bbase = Wg2p + lane * 16;
        for (int kit = 0; kit < 8; ++kit) {
            float v[8];
            load8(sm.act1 + m * LDACT + kit * 32 + q8, v);
            half8 ah, al; split8(v, ah, al);
            const _Float16* bp = bbase + (size_t)kit * 1024;
            half8 bh = *(const half8*)(bp);
            half8 bl = *(const half8*)(bp + 8);
            acc = __builtin_amdgcn_mfma_f32_16x16x32_f16(al, bh, acc, 0, 0, 0);
            acc = __builtin_amdgcn_mfma_f32_16x16x32_f16(ah, bl, acc, 0, 0, 0);
            acc = __builtin_amdgcn_mfma_f32_16x16x32_f16(ah, bh, acc, 0, 0, 0);
        }
        int col = lane & 15, q = lane >> 4;
        float bs = bg2[col];
#pragma unroll
        for (int r = 0; r < 4; ++r) {
            int s = w * 16 + q * 4 + r;
            float vv = acc[r] + bs;
            sm.feats[s * 16 + col] = vv;
            if (col == 0) { int n = n0 + s; if (n < Nsamp) out_sdf[n] = vv; }
        }
    }
    // no barrier: P6 only reads act1/wg2c0, writes its own act0 cells

    // ---- P6: g1 = (mask(h1)*wg2c0) @ Wg1T, gated by (h0>0)  -> act0
    mfma_gemm<8, false, false, true, true>(sm.act1, LDACT, sm.wg2c0, Wg1Tp, 8, nullptr,
                                           sm.act0, LDACT, lane, w & 1, (w >> 1) * 8);
    __syncthreads();

    // ---- P7: g0 = g1 @ Wg0T  -> act1 cols 0..63 (39 valid)
    mfma_gemm<2, false, false, false, false>(sm.act0, LDACT, nullptr, Wg0Tp, 8, nullptr,
                                             sm.act1, LDACT, lane, w & 1, (w >> 1) * 2);
    __syncthreads();

    // ---- P7b: grad through encoding, normal, alpha
    if (tid < TILE) {
        int s = tid;
        float g[3];
#pragma unroll
        for (int d = 0; d < 3; ++d) g[d] = sm.act1[s * LDACT + d];
#pragma unroll
        for (int f = 0; f < 6; ++f) {
            float freq = 3.14159265358979323846f * (float)(1 << f);
#pragma unroll
            for (int d = 0; d < 3; ++d) {
                float gs = sm.act1[s * LDACT + 3 + f * 6 + d];
                float gc = sm.act1[s * LDACT + 3 + f * 6 + 3 + d];
                float sv = sm.enc[s * LDENC + 3 + f * 6 + d];
                float cv = sm.enc[s * LDENC + 3 + f * 6 + 3 + d];
                g[d] += freq * (gs * cv - gc * sv);
            }
        }
        float gl = sqrtf(g[0] * g[0] + g[1] * g[1] + g[2] * g[2]);
        float invl = 1.f / (gl + 1e-10f);
        float nx = g[0] * invl, ny = g[1] * invl, nz = g[2] * invl;
        sm.nrm[s * 4 + 0] = nx; sm.nrm[s * 4 + 1] = ny; sm.nrm[s * 4 + 2] = nz;
        float dx = sm.dirs[s * 4 + 0], dy = sm.dirs[s * 4 + 1], dz = sm.dirs[s * 4 + 2];
        float dsdt = fminf(g[0] * dx + g[1] * dy + g[2] * dz, 0.f);
        float sdf = sm.feats[s * 16 + 0];
        float inv_s = __expf(s_var[0]);
        inv_s = fminf(fmaxf(inv_s, 1e-6f), 1e6f);
        float cdf = 1.f / (1.f + __expf(-inv_s * sdf));
        float rho = fmaxf(inv_s * (cdf - 1.f) * dsdt, 0.f);
        float alpha = 1.f - __expf(-rho * 0.005f);
        float a = fminf(fmaxf(alpha, 0.f), 1.f - 1e-7f);
        int n = n0 + s;
        if (n < Nsamp) {
            ws_a[n] = a;
            ws_nrm[n * 3 + 0] = nx; ws_nrm[n * 3 + 1] = ny; ws_nrm[n * 3 + 2] = nz;
        }
    }
    __syncthreads();

    // ---- P8a: cin = [t_dirs(3), feats(16), points(3), normal(3), 0pad] ld36
    // overlay cin onto act0 (g1 dead)
    float* cin = sm.act0;
    for (int i = tid; i < TILE * 36; i += NTHREADS) {
        int s = i / 36, c = i - s * 36;
        float v = 0.f;
        if      (c < 3)  v = sm.dirs[s * 4 + c];
        else if (c < 19) v = sm.feats[s * 16 + (c - 3)];
        else if (c < 22) v = sm.enc[s * LDENC + (c - 19)];
        else if (c < 25) v = sm.nrm[s * 4 + (c - 22)];
        cin[s * 36 + c] = v;
    }
    __syncthreads();

    // ---- P8: hc = relu(cin @ Wc0 + bc0)  -> act1   (K=32 padded)
    mfma_gemm<8, true, true, false, false>(cin, 36, nullptr, Wc0p, 1, bc0,
                                           sm.act1, LDACT, lane, w & 1, (w >> 1) * 8);
    __syncthreads();

    // ---- P9: rgb = sigmoid(hc @ Wc1 + bc1) (waves 0,1)
    if (w < 2) {
        f32x4 acc = (f32x4){0.f, 0.f, 0.f, 0.f};
        const int m = w * 16 + (lane & 15);
        const int q8 = (lane >> 4) * 8;
        const _Float16* bbase = Wc1p + lane * 16;
        for (int kit = 0; kit < 8; ++kit) {
            float v[8];
            load8(sm.act1 + m * LDACT + kit * 32 + q8, v);
            half8 ah, al; split8(v, ah, al);
            const _Float16* bp = bbase + (size_t)kit * 1024;
            half8 bh = *(const half8*)(bp);
            half8 bl = *(const half8*)(bp + 8);
            acc = __builtin_amdgcn_mfma_f32_16x16x32_f16(al, bh, acc, 0, 0, 0);
            acc = __builtin_amdgcn_mfma_f32_16x16x32_f16(ah, bl, acc, 0, 0, 0);
            acc = __builtin_amdgcn_mfma_f32_16x16x32_f16(ah, bh, acc, 0, 0, 0);
        }
        int col = lane & 15, q = lane >> 4;
        if (col < 3) {
#pragma unroll
            for (int r = 0; r < 4; ++r) {
                int s = w * 16 + q * 4 + r;
                float rgb = 1.f / (1.f + __expf(-(acc[r] + bc1[col])));
                int n = n0 + s;
                if (n < Nsamp) ws_rgb[n * 3 + col] = rgb;
            }
        }
    }
}

// ---------------- K3: per-ray compositing ----------------------------------
__global__ void k3_composite(
    const int* __restrict__ ray_idx, const float* __restrict__ t_starts,
    const float* __restrict__ ws_a, const float* __restrict__ ws_rgb,
    const float* __restrict__ ws_nrm,
    float* __restrict__ out_pc, float* __restrict__ out_pn,
    float* __restrict__ out_op, float* __restrict__ out_dp,
    float* __restrict__ out_w, int n_rays, int Nsamp)
{
    int r = blockIdx.x * blockDim.x + threadIdx.x;
    if (r >= n_rays) return;
    int lo = 0, hi = Nsamp;
    while (lo < hi) { int m = (lo + hi) >> 1; if (ray_idx[m] < r) lo = m + 1; else hi = m; }
    int start = lo;
    hi = Nsamp;
    while (lo < hi) { int m = (lo + hi) >> 1; if (ray_idx[m] < r + 1) lo = m + 1; else hi = m; }
    int end = lo;

    float T = 1.f, aco = 0.f, acd = 0.f;
    float c0 = 0.f, c1 = 0.f, c2 = 0.f, nx = 0.f, ny = 0.f, nz = 0.f;
    for (int n = start; n < end; ++n) {
        float a = ws_a[n];
        float wgt = a * T;
        T *= (1.f - a);
        out_w[n] = wgt;
        float mid = t_starts[n] + 0.0025f;
        aco += wgt; acd += wgt * mid;
        c0 += wgt * ws_rgb[n * 3 + 0];
        c1 += wgt * ws_rgb[n * 3 + 1];
        c2 += wgt * ws_rgb[n * 3 + 2];
        nx += wgt * ws_nrm[n * 3 + 0];
        ny += wgt * ws_nrm[n * 3 + 1];
        nz += wgt * ws_nrm[n * 3 + 2];
    }
    out_op[r] = aco;
    out_dp[r] = acd;
    out_pc[r * 3 + 0] = c0; out_pc[r * 3 + 1] = c1; out_pc[r * 3 + 2] = c2;
    float nl = sqrtf(nx * nx + ny * ny + nz * nz);
    float inv = 1.f / (nl + 1e-10f);
    out_pn[r * 3 + 0] = nx * inv; out_pn[r * 3 + 1] = ny * inv; out_pn[r * 3 + 2] = nz * inv;
}

// ---------------- K4: random_sdfs ------------------------------------------
__global__ __launch_bounds__(256) void k4_random(
    const float* __restrict__ pts,
    const float* __restrict__ Wg0, const float* __restrict__ bg0,
    const float* __restrict__ Wg1, const float* __restrict__ bg1,
    const float* __restrict__ Wg2, const float* __restrict__ bg2,
    float* __restrict__ out_rs, int n_rand)
{
    __shared__ float enc[40];
    __shared__ float h[256];
    __shared__ float red[256];
    int b = blockIdx.x;
    if (b >= n_rand) return;
    int tid = threadIdx.x;
    if (tid < 39) {
        int c = tid;
        float v;
        if (c < 3) v = pts[b * 3 + c];
        else {
            int e = c - 3, f = e / 6, r = e - f * 6;
            float freq = 3.14159265358979323846f * (float)(1 << f);
            int d = (r < 3) ? r : r - 3;
            float x = pts[b * 3 + d];
            v = (r < 3) ? sinf(freq * x) : cosf(freq * x);
        }
        enc[c] = v;
    }
    __syncthreads();
    {
        float z = bg0[tid];
        for (int m = 0; m < 39; ++m) z += enc[m] * Wg0[m * 256 + tid];
        h[tid] = fmaxf(z, 0.f);
    }
    __syncthreads();
    {
        float z = bg1[tid];
        for (int k = 0; k < 256; ++k) z += h[k] * Wg1[k * 256 + tid];
        float h1 = fmaxf(z, 0.f);
        red[tid] = h1 * Wg2[tid * 16];   // Wg2[:,0]
    }
    __syncthreads();
    for (int off = 128; off > 0; off >>= 1) {
        if (tid < off) red[tid] += red[tid + off];
        __syncthreads();
    }
    if (tid == 0) out_rs[b] = red[0] + bg2[0];
}

extern "C" void kernel_launch(void* const* d_in, const int* in_sizes, int n_in,
                              void* d_out, int out_size, void* d_ws, size_t ws_size,
                              hipStream_t stream)
{
    const float* rays_o   = (const float*)d_in[0];
    const float* rays_d   = (const float*)d_in[1];
    const int*   ray_idx  = (const int*)  d_in[2];
    const float* t_starts = (const float*)d_in[3];
    const float* rpts     = (const float*)d_in[4];
    const float* s_var    = (const float*)d_in[5];
    const float* Wg0 = (const float*)d_in[6];  const float* bg0 = (const float*)d_in[7];
    const float* Wg1 = (const float*)d_in[8];  const float* bg1 = (const float*)d_in[9];
    const float* Wg2 = (const float*)d_in[10]; const float* bg2 = (const float*)d_in[11];
    const float* Wc0 = (const float*)d_in[12]; const float* bc0 = (const float*)d_in[13];
    const float* Wc1 = (const float*)d_in[14]; const float* bc1 = (const float*)d_in[15];

    const int n_rays = in_sizes[0] / 3;
    const int Ns     = in_sizes[2];
    const int n_rand = in_sizes[4] / 3;

    float* out  = (float*)d_out;
    float* o_pc = out;
    float* o_pn = out + (size_t)3 * n_rays;
    float* o_op = out + (size_t)6 * n_rays;
    float* o_dp = out + (size_t)7 * n_rays;
    float* o_w  = out + (size_t)8 * n_rays;
    float* o_sdf = o_w + Ns;
    float* o_rs  = o_sdf + Ns;

    // ws: packed f16 weights first, then float scratch
    _Float16* hptr  = (_Float16*)d_ws;
    _Float16* Wg0p  = hptr;                 // 32768 halves
    _Float16* Wg1p  = Wg0p  + 32768;        // 131072
    _Float16* Wg1Tp = Wg1p  + 131072;       // 131072
    _Float16* Wg0Tp = Wg1Tp + 131072;       // 32768
    _Float16* Wc0p  = Wg0Tp + 32768;        // 16384
    _Float16* Wg2p  = Wc0p  + 16384;        // 8192
    _Float16* Wc1p  = Wg2p  + 8192;         // 8192  -> total 360448 halves
    float* fbase  = (float*)(hptr + 360448);
    float* ws_a   = fbase;
    float* ws_rgb = ws_a + Ns;
    float* ws_nrm = ws_rgb + (size_t)3 * Ns;

    hipLaunchKernelGGL(k0_pack, dim3(704), dim3(256), 0, stream,
                       Wg0, Wg1, Wg2, Wc0, Wc1,
                       Wg0p, Wg1p, Wg1Tp, Wg0Tp, Wc0p, Wg2p, Wc1p);
    hipLaunchKernelGGL(k2_mlp, dim3((Ns + TILE - 1) / TILE), dim3(NTHREADS), 0, stream,
                       rays_o, rays_d, ray_idx, t_starts, s_var,
                       bg0, bg1, Wg2, bg2, bc0, bc1,
                       Wg0p, Wg1p, Wg1Tp, Wg0Tp, Wc0p, Wg2p, Wc1p,
                       o_sdf, ws_a, ws_rgb, ws_nrm, Ns);
    hipLaunchKernelGGL(k4_random, dim3(n_rand), dim3(256), 0, stream,
                       rpts, Wg0, bg0, Wg1, bg1, Wg2, bg2, o_rs, n_rand);
    hipLaunchKernelGGL(k3_composite, dim3((n_rays + 255) / 256), dim3(256), 0, stream,
                       ray_idx, t_starts, ws_a, ws_rgb, ws_nrm,
                       o_pc, o_pn, o_op, o_dp, o_w, n_rays, Ns);
}

// Round 3
// 948.487 us; speedup vs baseline: 3.4876x; 1.1248x over previous
//
#include <hip/hip_runtime.h>
#include <math.h>

// ---------------------------------------------------------------------------
// NeuS-style fused renderer, split-f16 MFMA version, 512-thread blocks.
// All GEMMs run as v_mfma_f32_16x16x32_f16 with hi/lo split operands
// (3 MFMAs per logical tile -> ~f32 accuracy at 1/3 of 2.5PF).
// R3: 512 threads/block (8 waves), same 79KB LDS -> 4 waves/SIMD occupancy.
// ---------------------------------------------------------------------------

#define TILE 32
#define NTHREADS 512
#define LDACT 260   // stride-260 f32: 2-way bank alias only (free, m136)
#define LDENC 68

typedef _Float16 half8 __attribute__((ext_vector_type(8)));
typedef float f32x4 __attribute__((ext_vector_type(4)));

struct alignas(16) SMemK2 {
    float act0[TILE * LDACT];   // h0 -> g1 -> cin(overlay, ld36)
    float act1[TILE * LDACT];   // h1 -> (g0 cols 0..63) -> hc
    float enc [TILE * LDENC];   // [x(3), sin/cos(36), 0-pad to 63]
    float dirs[TILE * 4];
    float feats[TILE * 16];
    float nrm [TILE * 4];
    float wg2c0[256];           // Wg2[:,0]
};

__device__ __forceinline__ void load8(const float* p, float v[8]) {
    float4 a = *(const float4*)p, b = *(const float4*)(p + 4);
    v[0]=a.x; v[1]=a.y; v[2]=a.z; v[3]=a.w; v[4]=b.x; v[5]=b.y; v[6]=b.z; v[7]=b.w;
}

__device__ __forceinline__ void split8(const float v[8], half8& hi, half8& lo) {
#pragma unroll
    for (int j = 0; j < 8; ++j) {
        float x = v[j];
        _Float16 h = (_Float16)x;
        hi[j] = h;
        lo[j] = (_Float16)(x - (float)h);
    }
}

// Wave-level GEMM: C tile rows mt*16..+16, cols (ntbase..ntbase+NTPW)*16.
// A: f32 in LDS (row s, ld lda). B packed frag layout:
//   Bp[((nt*kiters + kit)*64 + lane)*16 + (0..7 hi | 8..15 lo)].
template<int NTPW, bool BIAS, bool RELU, bool MASK, bool AMASKG2>
__device__ __forceinline__ void mfma_gemm(
    const float* sA, int lda, const float* wg2c0,
    const _Float16* __restrict__ Bp, int kiters,
    const float* __restrict__ bias,
    float* sC, int ldc,
    int lane, int mt, int ntbase)
{
    f32x4 acc[NTPW];
#pragma unroll
    for (int t = 0; t < NTPW; ++t) acc[t] = (f32x4){0.f, 0.f, 0.f, 0.f};
    const int m  = mt * 16 + (lane & 15);
    const int q8 = (lane >> 4) * 8;
    const _Float16* bbase = Bp + (size_t)ntbase * kiters * 1024 + lane * 16;

    for (int kit = 0; kit < kiters; ++kit) {
        float v[8];
        load8(sA + m * lda + kit * 32 + q8, v);
        if (AMASKG2) {
            float wv[8];
            load8(wg2c0 + kit * 32 + q8, wv);   // quad-broadcast
#pragma unroll
            for (int j = 0; j < 8; ++j) v[j] = (v[j] > 0.f) ? wv[j] : 0.f;
        }
        half8 ah, al;
        split8(v, ah, al);
        const _Float16* bp = bbase + (size_t)kit * 1024;
        half8 bh[NTPW], bl[NTPW];
#pragma unroll
        for (int t = 0; t < NTPW; ++t) {
            const _Float16* bt = bp + (size_t)t * kiters * 1024;
            bh[t] = *(const half8*)(bt);
            bl[t] = *(const half8*)(bt + 8);
        }
        // grouped issue: NTPW independent chains per pass
#pragma unroll
        for (int t = 0; t < NTPW; ++t)
            acc[t] = __builtin_amdgcn_mfma_f32_16x16x32_f16(al, bh[t], acc[t], 0, 0, 0);
#pragma unroll
        for (int t = 0; t < NTPW; ++t)
            acc[t] = __builtin_amdgcn_mfma_f32_16x16x32_f16(ah, bl[t], acc[t], 0, 0, 0);
#pragma unroll
        for (int t = 0; t < NTPW; ++t)
            acc[t] = __builtin_amdgcn_mfma_f32_16x16x32_f16(ah, bh[t], acc[t], 0, 0, 0);
    }
    const int col = lane & 15, q = lane >> 4;
#pragma unroll
    for (int t = 0; t < NTPW; ++t) {
        int j = (ntbase + t) * 16 + col;
        float bs = BIAS ? bias[j] : 0.f;
#pragma unroll
        for (int r = 0; r < 4; ++r) {
            int s = mt * 16 + q * 4 + r;
            float vv = acc[t][r] + bs;
            if (RELU) vv = fmaxf(vv, 0.f);
            if (MASK) { float old = sC[s * ldc + j]; vv = (old > 0.f) ? vv : 0.f; }
            sC[s * ldc + j] = vv;
        }
    }
}

// ---------------- K0: pack weights to (hi|lo) B-fragment layout -------------
__global__ __launch_bounds__(256) void k0_pack(
    const float* __restrict__ Wg0, const float* __restrict__ Wg1,
    const float* __restrict__ Wg2, const float* __restrict__ Wc0,
    const float* __restrict__ Wc1,
    _Float16* __restrict__ Wg0p, _Float16* __restrict__ Wg1p,
    _Float16* __restrict__ Wg1Tp, _Float16* __restrict__ Wg0Tp,
    _Float16* __restrict__ Wc0p, _Float16* __restrict__ Wg2p,
    _Float16* __restrict__ Wc1p)
{
    int gid = blockIdx.x * 256 + threadIdx.x;
    if (gid >= 180224) return;
    int idx, kiters, mode;
    _Float16* dst;
    if      (gid <  16384) { idx = gid;          kiters = 2; dst = Wg0p;  mode = 0; }
    else if (gid <  81920) { idx = gid -  16384; kiters = 8; dst = Wg1p;  mode = 1; }
    else if (gid < 147456) { idx = gid -  81920; kiters = 8; dst = Wg1Tp; mode = 2; }
    else if (gid < 163840) { idx = gid - 147456; kiters = 8; dst = Wg0Tp; mode = 3; }
    else if (gid < 172032) { idx = gid - 163840; kiters = 1; dst = Wc0p;  mode = 4; }
    else if (gid < 176128) { idx = gid - 172032; kiters = 8; dst = Wg2p;  mode = 5; }
    else                   { idx = gid - 176128; kiters = 8; dst = Wc1p;  mode = 6; }
    int j = idx & 7, lane = (idx >> 3) & 63, rest = idx >> 9;
    int kit = rest % kiters, nt = rest / kiters;
    int k = kit * 32 + ((lane >> 4) << 3) + j;
    int n = (nt << 4) + (lane & 15);
    float val = 0.f;
    switch (mode) {
        case 0: val = (k < 39) ? Wg0[k * 256 + n] : 0.f; break;
        case 1: val = Wg1[k * 256 + n]; break;
        case 2: val = Wg1[n * 256 + k]; break;                // Wg1^T
        case 3: val = (n < 39) ? Wg0[n * 256 + k] : 0.f; break; // Wg0^T (N pad 64)
        case 4: val = (k < 25) ? Wc0[k * 256 + n] : 0.f; break;
        case 5: val = Wg2[k * 16 + n]; break;
        case 6: val = (n < 3) ? Wc1[k * 3 + n] : 0.f; break;
    }
    _Float16 h = (_Float16)val;
    _Float16 l = (_Float16)(val - (float)h);
    int off = ((nt * kiters + kit) * 64 + lane) * 16 + j;
    dst[off] = h;
    dst[off + 8] = l;
}

// ---------------- K2: the fused MLP (8 waves) ------------------------------
__global__ __launch_bounds__(512, 4) void k2_mlp(
    const float* __restrict__ rays_o, const float* __restrict__ rays_d,
    const int*   __restrict__ ray_idx, const float* __restrict__ t_starts,
    const float* __restrict__ s_var,
    const float* __restrict__ bg0, const float* __restrict__ bg1,
    const float* __restrict__ Wg2, const float* __restrict__ bg2,
    const float* __restrict__ bc0, const float* __restrict__ bc1,
    const _Float16* __restrict__ Wg0p, const _Float16* __restrict__ Wg1p,
    const _Float16* __restrict__ Wg1Tp, const _Float16* __restrict__ Wg0Tp,
    const _Float16* __restrict__ Wc0p, const _Float16* __restrict__ Wg2p,
    const _Float16* __restrict__ Wc1p,
    float* __restrict__ out_sdf, float* __restrict__ ws_a,
    float* __restrict__ ws_rgb, float* __restrict__ ws_nrm,
    int Nsamp)
{
    __shared__ SMemK2 sm;
    const int tid = threadIdx.x;
    const int lane = tid & 63;
    const int w = tid >> 6;          // 0..7
    const int mt = w & 1;            // row-tile
    const int ntg = w >> 1;          // 0..3 col-group
    const int n0 = blockIdx.x * TILE;

    // ---- P0: points, dirs, Wg2[:,0]
    if (tid < 256) sm.wg2c0[tid] = Wg2[tid * 16];
    if (tid < TILE) {
        int n = n0 + tid; if (n >= Nsamp) n = Nsamp - 1;
        int ri = ray_idx[n];
        float dx = rays_d[ri * 3 + 0], dy = rays_d[ri * 3 + 1], dz = rays_d[ri * 3 + 2];
        float inv = 1.f / (sqrtf(dx * dx + dy * dy + dz * dz) + 1e-10f);
        dx *= inv; dy *= inv; dz *= inv;
        float mid = t_starts[n] + 0.0025f;
        sm.dirs[tid * 4 + 0] = dx; sm.dirs[tid * 4 + 1] = dy; sm.dirs[tid * 4 + 2] = dz;
        sm.enc[tid * LDENC + 0] = rays_o[ri * 3 + 0] + dx * mid;
        sm.enc[tid * LDENC + 1] = rays_o[ri * 3 + 1] + dy * mid;
        sm.enc[tid * LDENC + 2] = rays_o[ri * 3 + 2] + dz * mid;
    }
    __syncthreads();

    // ---- P1: positional encoding + zero pad cols 39..67
    for (int i = tid; i < TILE * 36; i += NTHREADS) {
        int s = i & (TILE - 1);
        int e = i >> 5;                    // 0..35
        int f = e / 6, r = e - f * 6;
        float freq = 3.14159265358979323846f * (float)(1 << f);
        int d = (r < 3) ? r : r - 3;
        float x = sm.enc[s * LDENC + d];
        sm.enc[s * LDENC + 3 + e] = (r < 3) ? sinf(freq * x) : cosf(freq * x);
    }
    for (int i = tid; i < TILE * 29; i += NTHREADS) {
        int s = i / 29, c = 39 + (i - s * 29);
        sm.enc[s * LDENC + c] = 0.f;
    }
    __syncthreads();

    // ---- P2: h0 = relu(enc @ Wg0 + bg0) -> act0   (K=64 padded)
    mfma_gemm<4, true, true, false, false>(sm.enc, LDENC, nullptr, Wg0p, 2, bg0,
                                           sm.act0, LDACT, lane, mt, ntg * 4);
    __syncthreads();

    // ---- P3: h1 = relu(h0 @ Wg1 + bg1) -> act1
    mfma_gemm<4, true, true, false, false>(sm.act0, LDACT, nullptr, Wg1p, 8, bg1,
                                           sm.act1, LDACT, lane, mt, ntg * 4);
    __syncthreads();

    // ---- P4: feats = h1 @ Wg2 + bg2 (waves 0,1); sdf out
    if (w < 2) {
        f32x4 acc = (f32x4){0.f, 0.f, 0.f, 0.f};
        const int m = w * 16 + (lane & 15);
        const int q8 = (lane >> 4) * 8;
        const _Float16* bbase = Wg2p + lane * 16;
        for (int kit = 0; kit < 8; ++kit) {
            float v[8];
            load8(sm.act1 + m * LDACT + kit * 32 + q8, v);
            half8 ah, al; split8(v, ah, al);
            const _Float16* bp = bbase + (size_t)kit * 1024;
            half8 bh = *(const half8*)(bp);
            half8 bl = *(const half8*)(bp + 8);
            acc = __builtin_amdgcn_mfma_f32_16x16x32_f16(al, bh, acc, 0, 0, 0);
            acc = __builtin_amdgcn_mfma_f32_16x16x32_f16(ah, bl, acc, 0, 0, 0);
            acc = __builtin_amdgcn_mfma_f32_16x16x32_f16(ah, bh, acc, 0, 0, 0);
        }
        int col = lane & 15, q = lane >> 4;
        float bs = bg2[col];
#pragma unroll
        for (int r = 0; r < 4; ++r) {
            int s = w * 16 + q * 4 + r;
            float vv = acc[r] + bs;
            sm.feats[s * 16 + col] = vv;
            if (col == 0) { int n = n0 + s; if (n < Nsamp) out_sdf[n] = vv; }
        }
    }
    // no barrier: P6 reads act1/wg2c0 (stable) and each wave touches only its
    // own (mt,nt) act0 cells

    // ---- P6: g1 = (mask(h1)*wg2c0) @ Wg1T, gated by (h0>0)  -> act0
    mfma_gemm<4, false, false, true, true>(sm.act1, LDACT, sm.wg2c0, Wg1Tp, 8, nullptr,
                                           sm.act0, LDACT, lane, mt, ntg * 4);
    __syncthreads();

    // ---- P7: g0 = g1 @ Wg0T  -> act1 cols 0..63 (39 valid)
    mfma_gemm<1, false, false, false, false>(sm.act0, LDACT, nullptr, Wg0Tp, 8, nullptr,
                                             sm.act1, LDACT, lane, mt, ntg);
    __syncthreads();

    // ---- P7b: grad through encoding, normal, alpha
    if (tid < TILE) {
        int s = tid;
        float g[3];
#pragma unroll
        for (int d = 0; d < 3; ++d) g[d] = sm.act1[s * LDACT + d];
#pragma unroll
        for (int f = 0; f < 6; ++f) {
            float freq = 3.14159265358979323846f * (float)(1 << f);
#pragma unroll
            for (int d = 0; d < 3; ++d) {
                float gs = sm.act1[s * LDACT + 3 + f * 6 + d];
                float gc = sm.act1[s * LDACT + 3 + f * 6 + 3 + d];
                float sv = sm.enc[s * LDENC + 3 + f * 6 + d];
                float cv = sm.enc[s * LDENC + 3 + f * 6 + 3 + d];
                g[d] += freq * (gs * cv - gc * sv);
            }
        }
        float gl = sqrtf(g[0] * g[0] + g[1] * g[1] + g[2] * g[2]);
        float invl = 1.f / (gl + 1e-10f);
        float nx = g[0] * invl, ny = g[1] * invl, nz = g[2] * invl;
        sm.nrm[s * 4 + 0] = nx; sm.nrm[s * 4 + 1] = ny; sm.nrm[s * 4 + 2] = nz;
        float dx = sm.dirs[s * 4 + 0], dy = sm.dirs[s * 4 + 1], dz = sm.dirs[s * 4 + 2];
        float dsdt = fminf(g[0] * dx + g[1] * dy + g[2] * dz, 0.f);
        float sdf = sm.feats[s * 16 + 0];
        float inv_s = __expf(s_var[0]);
        inv_s = fminf(fmaxf(inv_s, 1e-6f), 1e6f);
        float cdf = 1.f / (1.f + __expf(-inv_s * sdf));
        float rho = fmaxf(inv_s * (cdf - 1.f) * dsdt, 0.f);
        float alpha = 1.f - __expf(-rho * 0.005f);
        float a = fminf(fmaxf(alpha, 0.f), 1.f - 1e-7f);
        int n = n0 + s;
        if (n < Nsamp) {
            ws_a[n] = a;
            ws_nrm[n * 3 + 0] = nx; ws_nrm[n * 3 + 1] = ny; ws_nrm[n * 3 + 2] = nz;
        }
    }
    __syncthreads();

    // ---- P8a: cin = [t_dirs(3), feats(16), points(3), normal(3), 0pad] ld36
    float* cin = sm.act0;   // overlay (g1 dead)
    for (int i = tid; i < TILE * 36; i += NTHREADS) {
        int s = i / 36, c = i - s * 36;
        float v = 0.f;
        if      (c < 3)  v = sm.dirs[s * 4 + c];
        else if (c < 19) v = sm.feats[s * 16 + (c - 3)];
        else if (c < 22) v = sm.enc[s * LDENC + (c - 19)];
        else if (c < 25) v = sm.nrm[s * 4 + (c - 22)];
        cin[s * 36 + c] = v;
    }
    __syncthreads();

    // ---- P8: hc = relu(cin @ Wc0 + bc0)  -> act1   (K=32 padded)
    mfma_gemm<4, true, true, false, false>(cin, 36, nullptr, Wc0p, 1, bc0,
                                           sm.act1, LDACT, lane, mt, ntg * 4);
    __syncthreads();

    // ---- P9: rgb = sigmoid(hc @ Wc1 + bc1) (waves 0,1)
    if (w < 2) {
        f32x4 acc = (f32x4){0.f, 0.f, 0.f, 0.f};
        const int m = w * 16 + (lane & 15);
        const int q8 = (lane >> 4) * 8;
        const _Float16* bbase = Wc1p + lane * 16;
        for (int kit = 0; kit < 8; ++kit) {
            float v[8];
            load8(sm.act1 + m * LDACT + kit * 32 + q8, v);
            half8 ah, al; split8(v, ah, al);
            const _Float16* bp = bbase + (size_t)kit * 1024;
            half8 bh = *(const half8*)(bp);
            half8 bl = *(const half8*)(bp + 8);
            acc = __builtin_amdgcn_mfma_f32_16x16x32_f16(al, bh, acc, 0, 0, 0);
            acc = __builtin_amdgcn_mfma_f32_16x16x32_f16(ah, bl, acc, 0, 0, 0);
            acc = __builtin_amdgcn_mfma_f32_16x16x32_f16(ah, bh, acc, 0, 0, 0);
        }
        int col = lane & 15, q = lane >> 4;
        if (col < 3) {
#pragma unroll
            for (int r = 0; r < 4; ++r) {
                int s = w * 16 + q * 4 + r;
                float rgb = 1.f / (1.f + __expf(-(acc[r] + bc1[col])));
                int n = n0 + s;
                if (n < Nsamp) ws_rgb[n * 3 + col] = rgb;
            }
        }
    }
}

// ---------------- K3: per-ray compositing ----------------------------------
__global__ void k3_composite(
    const int* __restrict__ ray_idx, const float* __restrict__ t_starts,
    const float* __restrict__ ws_a, const float* __restrict__ ws_rgb,
    const float* __restrict__ ws_nrm,
    float* __restrict__ out_pc, float* __restrict__ out_pn,
    float* __restrict__ out_op, float* __restrict__ out_dp,
    float* __restrict__ out_w, int n_rays, int Nsamp)
{
    int r = blockIdx.x * blockDim.x + threadIdx.x;
    if (r >= n_rays) return;
    int lo = 0, hi = Nsamp;
    while (lo < hi) { int m = (lo + hi) >> 1; if (ray_idx[m] < r) lo = m + 1; else hi = m; }
    int start = lo;
    hi = Nsamp;
    while (lo < hi) { int m = (lo + hi) >> 1; if (ray_idx[m] < r + 1) lo = m + 1; else hi = m; }
    int end = lo;

    float T = 1.f, aco = 0.f, acd = 0.f;
    float c0 = 0.f, c1 = 0.f, c2 = 0.f, nx = 0.f, ny = 0.f, nz = 0.f;
    for (int n = start; n < end; ++n) {
        float a = ws_a[n];
        float wgt = a * T;
        T *= (1.f - a);
        out_w[n] = wgt;
        float mid = t_starts[n] + 0.0025f;
        aco += wgt; acd += wgt * mid;
        c0 += wgt * ws_rgb[n * 3 + 0];
        c1 += wgt * ws_rgb[n * 3 + 1];
        c2 += wgt * ws_rgb[n * 3 + 2];
        nx += wgt * ws_nrm[n * 3 + 0];
        ny += wgt * ws_nrm[n * 3 + 1];
        nz += wgt * ws_nrm[n * 3 + 2];
    }
    out_op[r] = aco;
    out_dp[r] = acd;
    out_pc[r * 3 + 0] = c0; out_pc[r * 3 + 1] = c1; out_pc[r * 3 + 2] = c2;
    float nl = sqrtf(nx * nx + ny * ny + nz * nz);
    float inv = 1.f / (nl + 1e-10f);
    out_pn[r * 3 + 0] = nx * inv; out_pn[r * 3 + 1] = ny * inv; out_pn[r * 3 + 2] = nz * inv;
}

// ---------------- K4: random_sdfs ------------------------------------------
__global__ __launch_bounds__(256) void k4_random(
    const float* __restrict__ pts,
    const float* __restrict__ Wg0, const float* __restrict__ bg0,
    const float* __restrict__ Wg1, const float* __restrict__ bg1,
    const float* __restrict__ Wg2, const float* __restrict__ bg2,
    float* __restrict__ out_rs, int n_rand)
{
    __shared__ float enc[40];
    __shared__ float h[256];
    __shared__ float red[256];
    int b = blockIdx.x;
    if (b >= n_rand) return;
    int tid = threadIdx.x;
    if (tid < 39) {
        int c = tid;
        float v;
        if (c < 3) v = pts[b * 3 + c];
        else {
            int e = c - 3, f = e / 6, r = e - f * 6;
            float freq = 3.14159265358979323846f * (float)(1 << f);
            int d = (r < 3) ? r : r - 3;
            float x = pts[b * 3 + d];
            v = (r < 3) ? sinf(freq * x) : cosf(freq * x);
        }
        enc[c] = v;
    }
    __syncthreads();
    {
        float z = bg0[tid];
        for (int m = 0; m < 39; ++m) z += enc[m] * Wg0[m * 256 + tid];
        h[tid] = fmaxf(z, 0.f);
    }
    __syncthreads();
    {
        float z = bg1[tid];
        for (int k = 0; k < 256; ++k) z += h[k] * Wg1[k * 256 + tid];
        float h1 = fmaxf(z, 0.f);
        red[tid] = h1 * Wg2[tid * 16];   // Wg2[:,0]
    }
    __syncthreads();
    for (int off = 128; off > 0; off >>= 1) {
        if (tid < off) red[tid] += red[tid + off];
        __syncthreads();
    }
    if (tid == 0) out_rs[b] = red[0] + bg2[0];
}

extern "C" void kernel_launch(void* const* d_in, const int* in_sizes, int n_in,
                              void* d_out, int out_size, void* d_ws, size_t ws_size,
                              hipStream_t stream)
{
    const float* rays_o   = (const float*)d_in[0];
    const float* rays_d   = (const float*)d_in[1];
    const int*   ray_idx  = (const int*)  d_in[2];
    const float* t_starts = (const float*)d_in[3];
    const float* rpts     = (const float*)d_in[4];
    const float* s_var    = (const float*)d_in[5];
    const float* Wg0 = (const float*)d_in[6];  const float* bg0 = (const float*)d_in[7];
    const float* Wg1 = (const float*)d_in[8];  const float* bg1 = (const float*)d_in[9];
    const float* Wg2 = (const float*)d_in[10]; const float* bg2 = (const float*)d_in[11];
    const float* Wc0 = (const float*)d_in[12]; const float* bc0 = (const float*)d_in[13];
    const float* Wc1 = (const float*)d_in[14]; const float* bc1 = (const float*)d_in[15];

    const int n_rays = in_sizes[0] / 3;
    const int Ns     = in_sizes[2];
    const int n_rand = in_sizes[4] / 3;

    float* out  = (float*)d_out;
    float* o_pc = out;
    float* o_pn = out + (size_t)3 * n_rays;
    float* o_op = out + (size_t)6 * n_rays;
    float* o_dp = out + (size_t)7 * n_rays;
    float* o_w  = out + (size_t)8 * n_rays;
    float* o_sdf = o_w + Ns;
    float* o_rs  = o_sdf + Ns;

    // ws: packed f16 weights first, then float scratch
    _Float16* hptr  = (_Float16*)d_ws;
    _Float16* Wg0p  = hptr;                 // 32768 halves
    _Float16* Wg1p  = Wg0p  + 32768;        // 131072
    _Float16* Wg1Tp = Wg1p  + 131072;       // 131072
    _Float16* Wg0Tp = Wg1Tp + 131072;       // 32768
    _Float16* Wc0p  = Wg0Tp + 32768;        // 16384
    _Float16* Wg2p  = Wc0p  + 16384;        // 8192
    _Float16* Wc1p  = Wg2p  + 8192;         // 8192  -> total 360448 halves
    float* fbase  = (float*)(hptr + 360448);
    float* ws_a   = fbase;
    float* ws_rgb = ws_a + Ns;
    float* ws_nrm = ws_rgb + (size_t)3 * Ns;

    hipLaunchKernelGGL(k0_pack, dim3(704), dim3(256), 0, stream,
                       Wg0, Wg1, Wg2, Wc0, Wc1,
                       Wg0p, Wg1p, Wg1Tp, Wg0Tp, Wc0p, Wg2p, Wc1p);
    hipLaunchKernelGGL(k2_mlp, dim3((Ns + TILE - 1) / TILE), dim3(NTHREADS), 0, stream,
                       rays_o, rays_d, ray_idx, t_starts, s_var,
                       bg0, bg1, Wg2, bg2, bc0, bc1,
                       Wg0p, Wg1p, Wg1Tp, Wg0Tp, Wc0p, Wg2p, Wc1p,
                       o_sdf, ws_a, ws_rgb, ws_nrm, Ns);
    hipLaunchKernelGGL(k4_random, dim3(n_rand), dim3(256), 0, stream,
                       rpts, Wg0, bg0, Wg1, bg1, Wg2, bg2, o_rs, n_rand);
    hipLaunchKernelGGL(k3_composite, dim3((n_rays + 255) / 256), dim3(256), 0, stream,
                       ray_idx, t_starts, ws_a, ws_rgb, ws_nrm,
                       o_pc, o_pn, o_op, o_dp, o_w, n_rays, Ns);
}